// Round 1
// baseline (6952.904 us; speedup 1.0000x reference)
//
#include <hip/hip_runtime.h>
#include <stdint.h>

#define SLEN 4096
#define CLEN 16
#define EDIM 256
#define HDIM 512
#define CHD  4
#define NLBL 64
#define KIN  260   /* EDIM + CHD */
#define G4H  2048  /* 4*HDIM */

typedef unsigned long long u64;

__device__ __forceinline__ float sigf(float x){ return 1.0f/(1.0f+__expf(-x)); }

/* ---------------- char-level LSTM: one thread per word ---------------- */
__global__ void k_char_lstm(const float* __restrict__ chars, const int* __restrict__ lens,
                            const float* __restrict__ Wih, const float* __restrict__ Whh,
                            const float* __restrict__ bih, const float* __restrict__ bhh,
                            float* __restrict__ h_char){
  int s = blockIdx.x*blockDim.x + threadIdx.x;
  if (s >= SLEN) return;
  float wih[16], bb[16], whh[16][4];
  #pragma unroll
  for(int r=0;r<16;r++){
    wih[r]=Wih[r]; bb[r]=bih[r]+bhh[r];
    #pragma unroll
    for(int k=0;k<4;k++) whh[r][k]=Whh[r*4+k];
  }
  /* load the 16 chars of this word (64B contiguous per thread) */
  float x[16];
  #pragma unroll
  for(int i=0;i<4;i++){
    float4 v = *(const float4*)&chars[s*CLEN + 4*i];
    x[4*i+0]=v.x; x[4*i+1]=v.y; x[4*i+2]=v.z; x[4*i+3]=v.w;
  }
  float h[4]={0,0,0,0}, c[4]={0,0,0,0};
  int len = lens[s];
  #pragma unroll 1
  for(int t=0;t<CLEN;t++){
    float g[16];
    #pragma unroll
    for(int r=0;r<16;r++){
      float a = fmaf(x[t], wih[r], bb[r]);
      #pragma unroll
      for(int k=0;k<4;k++) a = fmaf(h[k], whh[r][k], a);
      g[r]=a;
    }
    bool m = t < len;
    #pragma unroll
    for(int j=0;j<4;j++){
      float ig=sigf(g[j]), fg=sigf(g[4+j]), gg=tanhf(g[8+j]), og=sigf(g[12+j]);
      float cn = fg*c[j] + ig*gg;
      float hn = og*tanhf(cn);
      if(m){ c[j]=cn; h[j]=hn; }
    }
  }
  #pragma unroll
  for(int j=0;j<4;j++) h_char[s*CHD+j]=h[j];
}

/* ------------- gather emb rows + h_char into word_in[4096][260] ------------- */
__global__ void k_gather(const int* __restrict__ sent, const float* __restrict__ emb,
                         const float* __restrict__ h_char, float* __restrict__ win){
  int s = blockIdx.x; int l = threadIdx.x; /* 64 threads */
  int row = sent[s];
  float4 v = *(const float4*)&emb[(size_t)row*EDIM + 4*l];
  *(float4*)&win[(size_t)s*KIN + 4*l] = v;
  if (l < CHD) win[(size_t)s*KIN + EDIM + l] = h_char[s*CHD + l];
}

/* ------------- gx = word_in @ W_ih_w.T  (M=4096,N=2048,K=260) ------------- */
#define BK 20
__global__ __launch_bounds__(256) void k_gemm_gx(const float* __restrict__ win,
                          const float* __restrict__ Wihw, float* __restrict__ gx){
  __shared__ float As[BK][68];
  __shared__ float Bs[BK][68];
  int s0 = blockIdx.x*64, n0 = blockIdx.y*64;
  int tid = threadIdx.x;
  int tm = tid>>4, tn = tid&15;
  float acc[4][4] = {};
  for(int k0=0;k0<KIN;k0+=BK){
    __syncthreads();
    #pragma unroll
    for(int i=0;i<5;i++){
      int e = tid + i*256;          /* 1280 elements */
      int m = e/BK, kk = e - m*BK;
      As[kk][m] = win[(size_t)(s0+m)*KIN + k0+kk];
      Bs[kk][m] = Wihw[(size_t)(n0+m)*KIN + k0+kk];
    }
    __syncthreads();
    #pragma unroll
    for(int kk=0;kk<BK;kk++){
      float4 a4 = *(const float4*)&As[kk][tm*4];
      float4 b4 = *(const float4*)&Bs[kk][tn*4];
      float av[4]={a4.x,a4.y,a4.z,a4.w};
      float bv[4]={b4.x,b4.y,b4.z,b4.w};
      #pragma unroll
      for(int i=0;i<4;i++)
        #pragma unroll
        for(int j=0;j<4;j++)
          acc[i][j] = fmaf(av[i], bv[j], acc[i][j]);
    }
  }
  #pragma unroll
  for(int i=0;i<4;i++){
    float4 o; o.x=acc[i][0]; o.y=acc[i][1]; o.z=acc[i][2]; o.w=acc[i][3];
    *(float4*)&gx[(size_t)(s0+tm*4+i)*G4H + n0 + tn*4] = o;
  }
}

/* ------------- word-level LSTM: 32 persistent WGs, packed tag+value comm ------------- */
__global__ __launch_bounds__(512) void k_word_lstm(const float* __restrict__ gx,
    const float* __restrict__ Whh, const float* __restrict__ bih, const float* __restrict__ bhh,
    u64* __restrict__ comm, float* __restrict__ hs){
  __shared__ float h_lds[8*68];      /* 8 chunks of 64, stride 68 for bank spread */
  __shared__ float gatebuf[64];
  const int tid = threadIdx.x;
  const int g   = blockIdx.x;        /* WG owns h indices [16g, 16g+16) */
  const int r   = tid>>3;            /* local gate-row 0..63 */
  const int cch = tid&7;             /* 64-wide k-chunk */
  const int gate = r>>4, jl = r&15;
  const int R = gate*HDIM + g*16 + jl;
  /* resident weight slice: W_hh_w[R][cch*64 .. cch*64+63] in 64 VGPRs */
  float4 w4[16];
  #pragma unroll
  for(int i=0;i<16;i++) w4[i] = *(const float4*)&Whh[(size_t)R*HDIM + cch*64 + 4*i];
  /* writer lanes (tid<16) own c-state + biases for h index gi */
  float cst = 0.f;
  float bsum[4];
  const int gi = g*16 + (tid & 15);
  if (tid<16){
    #pragma unroll
    for(int j=0;j<4;j++) bsum[j] = bih[j*HDIM + gi] + bhh[j*HDIM + gi];
  }
  for(int t=0;t<SLEN;t++){
    /* prefetch gx for this step (latency hidden under the poll) */
    float gxv[4];
    if (tid<16){
      #pragma unroll
      for(int j=0;j<4;j++) gxv[j] = gx[(size_t)t*G4H + j*HDIM + gi];
    }
    /* obtain h_t[tid] : poll packed {tag,value} slot (agent scope, no fences needed) */
    float hv = 0.f;
    if (t>0){
      const u64* slot = &comm[(size_t)t*HDIM + tid];
      u64 v;
      do { v = __hip_atomic_load(slot, __ATOMIC_RELAXED, __HIP_MEMORY_SCOPE_AGENT); }
      while ((unsigned)(v>>32) != (unsigned)t);
      union{unsigned u; float f;} cv; cv.u = (unsigned)v; hv = cv.f;
    }
    h_lds[(tid>>6)*68 + (tid&63)] = hv;
    __syncthreads();
    /* partial dot: 64 MACs from resident weights, h broadcast from LDS */
    float acc = 0.f;
    #pragma unroll
    for(int i=0;i<16;i++){
      float4 hh = *(const float4*)&h_lds[cch*68 + 4*i];
      acc = fmaf(w4[i].x, hh.x, acc);
      acc = fmaf(w4[i].y, hh.y, acc);
      acc = fmaf(w4[i].z, hh.z, acc);
      acc = fmaf(w4[i].w, hh.w, acc);
    }
    acc += __shfl_xor(acc,1);
    acc += __shfl_xor(acc,2);
    acc += __shfl_xor(acc,4);
    if (cch==0) gatebuf[r] = acc;
    __syncthreads();
    if (tid<16){
      float gi_ = gatebuf[tid]    + gxv[0] + bsum[0];
      float gf_ = gatebuf[16+tid] + gxv[1] + bsum[1];
      float gg_ = gatebuf[32+tid] + gxv[2] + bsum[2];
      float go_ = gatebuf[48+tid] + gxv[3] + bsum[3];
      float cn = sigf(gf_)*cst + sigf(gi_)*tanhf(gg_);
      float hn = sigf(go_)*tanhf(cn);
      cst = cn;
      hs[(size_t)t*HDIM + gi] = hn;
      union{float f; unsigned u;} hb; hb.f = hn;
      u64 pk = ((u64)(unsigned)(t+1)<<32) | (u64)hb.u;
      __hip_atomic_store(&comm[(size_t)(t+1)*HDIM + gi], pk,
                         __ATOMIC_RELAXED, __HIP_MEMORY_SCOPE_AGENT);
    }
  }
}

/* ------------- logits + log_softmax ------------- */
__global__ __launch_bounds__(256) void k_out(const float* __restrict__ hs,
        const float* __restrict__ Wout, const float* __restrict__ bout,
        float* __restrict__ out){
  __shared__ float hsub[HDIM];
  __shared__ float lg[NLBL];
  int s = blockIdx.x, tid = threadIdx.x;
  hsub[tid]       = hs[(size_t)s*HDIM + tid];
  hsub[tid+256]   = hs[(size_t)s*HDIM + tid + 256];
  __syncthreads();
  int l = tid>>2, q = tid&3;
  float a = 0.f;
  const float* wr = &Wout[(size_t)l*HDIM + q*128];
  const float* hr = &hsub[q*128];
  #pragma unroll 8
  for(int i=0;i<128;i++) a = fmaf(hr[i], wr[i], a);
  a += __shfl_xor(a,1);
  a += __shfl_xor(a,2);
  if (q==0) lg[l] = a + bout[l];
  __syncthreads();
  if (tid < NLBL){
    float x = lg[tid];
    float mx = x;
    #pragma unroll
    for(int m=32;m>=1;m>>=1) mx = fmaxf(mx, __shfl_xor(mx,m));
    float ex = __expf(x-mx);
    float sm = ex;
    #pragma unroll
    for(int m=32;m>=1;m>>=1) sm += __shfl_xor(sm,m);
    out[(size_t)s*NLBL + tid] = x - mx - logf(sm);
  }
}

extern "C" void kernel_launch(void* const* d_in, const int* in_sizes, int n_in,
                              void* d_out, int out_size, void* d_ws, size_t ws_size,
                              hipStream_t stream){
  const int*   sent  = (const int*)d_in[0];
  const float* chars = (const float*)d_in[1];
  const int*   lens  = (const int*)d_in[2];
  const float* emb   = (const float*)d_in[3];
  const float* Wihc  = (const float*)d_in[4];
  const float* Whhc  = (const float*)d_in[5];
  const float* bihc  = (const float*)d_in[6];
  const float* bhhc  = (const float*)d_in[7];
  const float* Wihw  = (const float*)d_in[8];
  const float* Whhw  = (const float*)d_in[9];
  const float* bihw  = (const float*)d_in[10];
  const float* bhhw  = (const float*)d_in[11];
  const float* Wout  = (const float*)d_in[12];
  const float* bout  = (const float*)d_in[13];
  float* out = (float*)d_out;

  /* workspace layout (floats):
     h_char 16384 | word_in 1064960 | gx 8388608 | hs 2097152 | comm (4097*512 u64)
     total ~60.1 MB */
  float* h_char = (float*)d_ws;
  float* win    = h_char + 16384;
  float* gx     = win + (size_t)SLEN*KIN;
  float* hs     = gx + (size_t)SLEN*G4H;
  u64*   comm   = (u64*)(hs + (size_t)SLEN*HDIM);

  hipMemsetAsync(comm, 0, (size_t)(SLEN+1)*HDIM*sizeof(u64), stream);
  k_char_lstm<<<SLEN/256, 256, 0, stream>>>(chars,lens,Wihc,Whhc,bihc,bhhc,h_char);
  k_gather<<<SLEN, 64, 0, stream>>>(sent,emb,h_char,win);
  k_gemm_gx<<<dim3(SLEN/64, G4H/64), 256, 0, stream>>>(win,Wihw,gx);
  k_word_lstm<<<HDIM/16, 512, 0, stream>>>(gx,Whhw,bihw,bhhw,comm,hs);
  k_out<<<SLEN, 256, 0, stream>>>(hs,Wout,bout,out);
}